// Round 1
// baseline (1349.544 us; speedup 1.0000x reference)
//
#include <hip/hip_runtime.h>
#include <math.h>

// GCN: 7 graph-conv layers. N=65536 nodes, E=1048576 edges, feat 128->64(x6)->40.
// Strategy: build dst-CSR once per call, then per layer {dense GEMM, pull-aggregate}.

constexpr int NFEAT = 128, NHID = 64, NCLASS = 40;

__global__ void hist_k(const int* __restrict__ dst, int* __restrict__ cnt, int E) {
  int i = blockIdx.x * blockDim.x + threadIdx.x;
  if (i < E) atomicAdd(&cnt[dst[i]], 1);
}

__global__ void scan1_k(const int* __restrict__ cnt, int* __restrict__ off,
                        int* __restrict__ bsum, int n) {
  __shared__ int tmp[256];
  int tid = threadIdx.x;
  int i = blockIdx.x * 256 + tid;
  int v = (i < n) ? cnt[i] : 0;
  tmp[tid] = v;
  __syncthreads();
  for (int d = 1; d < 256; d <<= 1) {
    int t = (tid >= d) ? tmp[tid - d] : 0;
    __syncthreads();
    tmp[tid] += t;
    __syncthreads();
  }
  if (i < n) off[i] = tmp[tid] - v;  // exclusive
  if (tid == 255) bsum[blockIdx.x] = tmp[255];
}

__global__ void scan2_k(int* __restrict__ bsum, int nb) {
  __shared__ int tmp[256];
  int tid = threadIdx.x;
  int v = (tid < nb) ? bsum[tid] : 0;
  tmp[tid] = v;
  __syncthreads();
  for (int d = 1; d < 256; d <<= 1) {
    int t = (tid >= d) ? tmp[tid - d] : 0;
    __syncthreads();
    tmp[tid] += t;
    __syncthreads();
  }
  if (tid < nb) bsum[tid] = tmp[tid] - v;  // exclusive
}

__global__ void scan3_k(int* __restrict__ off, const int* __restrict__ bsum, int n, int E) {
  int i = blockIdx.x * blockDim.x + threadIdx.x;
  if (i < n) off[i] += bsum[i >> 8];
  if (i == 0) off[n] = E;
}

__global__ void fill_k(const int* __restrict__ src, const int* __restrict__ dst,
                       const float* __restrict__ w, const int* __restrict__ off,
                       int* __restrict__ cur, int2* __restrict__ edata, int E) {
  int i = blockIdx.x * blockDim.x + threadIdx.x;
  if (i < E) {
    int d = dst[i];
    int pos = off[d] + atomicAdd(&cur[d], 1);
    edata[pos] = make_int2(src[i], __float_as_int(w[i]));
  }
}

// One wave per output row; lane = output column. W staged in LDS.
template<int FI, int FO>
__global__ void gemm_k(const float* __restrict__ h, const float* __restrict__ W,
                       float* __restrict__ out, int n) {
  __shared__ float Wl[FI * FO + 64];  // +64 pad: lanes >= FO read junk harmlessly
  int tid = threadIdx.x;
  for (int i = tid; i < FI * FO; i += 256) Wl[i] = W[i];
  __syncthreads();
  int lane = tid & 63;
  int row = blockIdx.x * 4 + (tid >> 6);
  if (row >= n) return;
  float hv0 = h[row * FI + lane];
  float hv1 = (FI > 64) ? h[row * FI + 64 + lane] : 0.0f;
  float acc = 0.0f;
#pragma unroll
  for (int k = 0; k < 64; ++k)
    acc += __shfl(hv0, k, 64) * Wl[k * FO + lane];
  if (FI > 64) {
#pragma unroll
    for (int k = 0; k < 64; ++k)
      acc += __shfl(hv1, k, 64) * Wl[(64 + k) * FO + lane];
  }
  if (lane < FO) out[row * FO + lane] = acc;
}

// Pull aggregation: one wave per node, lane = feature (FO=64).
__global__ void agg_k(const float* __restrict__ support,
                      const int2* __restrict__ edata,
                      const int* __restrict__ off,
                      const float* __restrict__ bias,
                      const float* __restrict__ resid,
                      float* __restrict__ out,
                      int n, int do_relu) {
  int tid = blockIdx.x * blockDim.x + threadIdx.x;
  int wid = tid >> 6, lane = tid & 63;
  if (wid >= n) return;
  int e0 = off[wid], e1 = off[wid + 1];
  float acc = 0.0f;
  for (int e = e0; e < e1; ++e) {
    int2 p = edata[e];
    acc += __int_as_float(p.y) * support[p.x * 64 + lane];
  }
  float v = acc + bias[lane];
  if (do_relu) v = fmaxf(v, 0.0f);
  if (resid) v += resid[wid * 64 + lane];
  out[wid * 64 + lane] = v;
}

// Final layer: FO=40 aggregation + bias + log_softmax, one wave per node.
__global__ void agg_final_k(const float* __restrict__ support,
                            const int2* __restrict__ edata,
                            const int* __restrict__ off,
                            const float* __restrict__ bias,
                            float* __restrict__ out, int n) {
  int tid = blockIdx.x * blockDim.x + threadIdx.x;
  int wid = tid >> 6, lane = tid & 63;
  if (wid >= n) return;
  int e0 = off[wid], e1 = off[wid + 1];
  float acc = 0.0f;
  if (lane < NCLASS) {
    for (int e = e0; e < e1; ++e) {
      int2 p = edata[e];
      acc += __int_as_float(p.y) * support[p.x * NCLASS + lane];
    }
    acc += bias[lane];
  }
  float v = (lane < NCLASS) ? acc : -INFINITY;
  float m = v;
#pragma unroll
  for (int d = 32; d; d >>= 1) m = fmaxf(m, __shfl_xor(m, d, 64));
  float ex = (lane < NCLASS) ? expf(v - m) : 0.0f;
  float s = ex;
#pragma unroll
  for (int d = 32; d; d >>= 1) s += __shfl_xor(s, d, 64);
  if (lane < NCLASS) out[wid * NCLASS + lane] = (v - m) - logf(s);
}

extern "C" void kernel_launch(void* const* d_in, const int* in_sizes, int n_in,
                              void* d_out, int out_size, void* d_ws, size_t ws_size,
                              hipStream_t stream) {
  const float* x   = (const float*)d_in[0];
  const int*   src = (const int*)d_in[1];
  const int*   dst = (const int*)d_in[2];
  const float* ew  = (const float*)d_in[3];
  const float* W[7]; const float* b[7];
  for (int i = 0; i < 7; ++i) {
    W[i] = (const float*)d_in[4 + 2 * i];
    b[i] = (const float*)d_in[5 + 2 * i];
  }
  int N = in_sizes[0] / NFEAT;   // 65536
  int E = in_sizes[1];           // 1048576

  char* ws = (char*)d_ws;
  int*   off     = (int*)(ws + 0);                    // (N+1) ints
  int*   bsum    = (int*)(ws + (1ll << 20));          // 256 ints
  int*   cnt     = (int*)(ws + (2ll << 20));          // N ints
  int2*  edata   = (int2*)(ws + (4ll << 20));         // E int2 = 8MB
  float* support = (float*)(ws + (16ll << 20));       // N*64 f32 = 16MB
  float* hA      = (float*)(ws + (32ll << 20));       // 16MB
  float* hB      = (float*)(ws + (48ll << 20));       // 16MB

  // ---- build dst-CSR ----
  hipMemsetAsync(cnt, 0, (size_t)N * sizeof(int), stream);
  hist_k<<<(E + 255) / 256, 256, 0, stream>>>(dst, cnt, E);
  int nb = (N + 255) / 256;  // 256 blocks
  scan1_k<<<nb, 256, 0, stream>>>(cnt, off, bsum, N);
  scan2_k<<<1, 256, 0, stream>>>(bsum, nb);
  scan3_k<<<nb, 256, 0, stream>>>(off, bsum, N, E);
  hipMemsetAsync(cnt, 0, (size_t)N * sizeof(int), stream);
  fill_k<<<(E + 255) / 256, 256, 0, stream>>>(src, dst, ew, off, cnt, edata, E);

  int gb = N / 4;  // 4 waves (rows/nodes) per 256-thread block

  // L1: x[128] -> 64, relu
  gemm_k<128, 64><<<gb, 256, 0, stream>>>(x, W[0], support, N);
  agg_k<<<gb, 256, 0, stream>>>(support, edata, off, b[0], nullptr, hA, N, 1);
  // L2
  gemm_k<64, 64><<<gb, 256, 0, stream>>>(hA, W[1], support, N);
  agg_k<<<gb, 256, 0, stream>>>(support, edata, off, b[1], nullptr, hB, N, 1);
  // L3: + residual (h2 = hB)
  gemm_k<64, 64><<<gb, 256, 0, stream>>>(hB, W[2], support, N);
  agg_k<<<gb, 256, 0, stream>>>(support, edata, off, b[2], hB, hA, N, 1);
  // L4: + residual (h3 = hA)
  gemm_k<64, 64><<<gb, 256, 0, stream>>>(hA, W[3], support, N);
  agg_k<<<gb, 256, 0, stream>>>(support, edata, off, b[3], hA, hB, N, 1);
  // L5: + residual (h4 = hB)
  gemm_k<64, 64><<<gb, 256, 0, stream>>>(hB, W[4], support, N);
  agg_k<<<gb, 256, 0, stream>>>(support, edata, off, b[4], hB, hA, N, 1);
  // L6
  gemm_k<64, 64><<<gb, 256, 0, stream>>>(hA, W[5], support, N);
  agg_k<<<gb, 256, 0, stream>>>(support, edata, off, b[5], nullptr, hB, N, 1);
  // L7: 64 -> 40, + log_softmax
  gemm_k<64, 40><<<gb, 256, 0, stream>>>(hB, W[6], support, N);
  agg_final_k<<<gb, 256, 0, stream>>>(support, edata, off, b[6], (float*)d_out, N);
}

// Round 2
// 589.824 us; speedup vs baseline: 2.2880x; 2.2880x over previous
//
#include <hip/hip_runtime.h>
#include <math.h>

// GCN: 7 graph-conv layers. N=65536 nodes, E=1048576 edges, feat 128->64(x6)->40.
// dst-CSR built once per call; per layer {register-blocked GEMM, pull-aggregate}.

constexpr int NFEAT = 128, NHID = 64, NCLASS = 40;

__global__ void hist_k(const int* __restrict__ dst, int* __restrict__ cnt, int E) {
  int i = blockIdx.x * blockDim.x + threadIdx.x;
  if (i < E) atomicAdd(&cnt[dst[i]], 1);
}

__global__ void scan1_k(const int* __restrict__ cnt, int* __restrict__ off,
                        int* __restrict__ bsum, int n) {
  __shared__ int tmp[256];
  int tid = threadIdx.x;
  int i = blockIdx.x * 256 + tid;
  int v = (i < n) ? cnt[i] : 0;
  tmp[tid] = v;
  __syncthreads();
  for (int d = 1; d < 256; d <<= 1) {
    int t = (tid >= d) ? tmp[tid - d] : 0;
    __syncthreads();
    tmp[tid] += t;
    __syncthreads();
  }
  if (i < n) off[i] = tmp[tid] - v;  // exclusive
  if (tid == 255) bsum[blockIdx.x] = tmp[255];
}

__global__ void scan2_k(int* __restrict__ bsum, int nb) {
  __shared__ int tmp[256];
  int tid = threadIdx.x;
  int v = (tid < nb) ? bsum[tid] : 0;
  tmp[tid] = v;
  __syncthreads();
  for (int d = 1; d < 256; d <<= 1) {
    int t = (tid >= d) ? tmp[tid - d] : 0;
    __syncthreads();
    tmp[tid] += t;
    __syncthreads();
  }
  if (tid < nb) bsum[tid] = tmp[tid] - v;  // exclusive
}

__global__ void scan3_k(int* __restrict__ off, const int* __restrict__ bsum, int n, int E) {
  int i = blockIdx.x * blockDim.x + threadIdx.x;
  if (i < n) off[i] += bsum[i >> 8];
  if (i == 0) off[n] = E;
}

__global__ void fill_k(const int* __restrict__ src, const int* __restrict__ dst,
                       const float* __restrict__ w, const int* __restrict__ off,
                       int* __restrict__ cur, int2* __restrict__ edata, int E) {
  int i = blockIdx.x * blockDim.x + threadIdx.x;
  if (i < E) {
    int d = dst[i];
    int pos = off[d] + atomicAdd(&cur[d], 1);
    edata[pos] = make_int2(src[i], __float_as_int(w[i]));
  }
}

// Register-blocked GEMM: 64x64 output tile / 256-thread block, 4x4 per thread.
// K staged in chunks of 64 through LDS (h tile padded stride 68; W chunk [64][64]).
template<int FI, int FO>
__global__ __launch_bounds__(256) void gemm_k(const float* __restrict__ h,
                                              const float* __restrict__ W,
                                              float* __restrict__ out, int n) {
  constexpr int HS = 68;            // h_lds row stride (floats), 16B-aligned, pad 4
  __shared__ float hl[64 * HS];     // 17408 B
  __shared__ float wl[64 * 64];     // 16384 B
  int tid = threadIdx.x;
  int row0 = blockIdx.x * 64;
  int tx = tid & 15, ty = tid >> 4;   // col group, row group

  float acc[4][4] = {};

  for (int kc = 0; kc < FI; kc += 64) {
    // stage h chunk: rows row0..row0+63, cols kc..kc+63
    {
      const float* hb = h + (size_t)row0 * FI + kc;
      for (int i = tid; i < 64 * 16; i += 256) {
        int r = i >> 4, kk = (i & 15) << 2;
        float4 v = *(const float4*)(hb + (size_t)r * FI + kk);
        *(float4*)&hl[r * HS + kk] = v;
      }
    }
    // stage W chunk: rows kc..kc+63, cols 0..63 (zero-padded if FO<64)
    if (FO == 64) {
      const float4* Wb = (const float4*)(W + (size_t)kc * 64);
      for (int i = tid; i < 64 * 16; i += 256) ((float4*)wl)[i] = Wb[i];
    } else {
      for (int i = tid; i < 64 * 64; i += 256) wl[i] = 0.0f;
      __syncthreads();
      for (int i = tid; i < 64 * FO; i += 256)
        wl[(i / FO) * 64 + (i % FO)] = W[(size_t)(kc + i / FO) * FO + (i % FO)];
    }
    __syncthreads();

    for (int k4 = 0; k4 < 64; k4 += 4) {
      float4 a[4];
#pragma unroll
      for (int r = 0; r < 4; ++r)
        a[r] = *(const float4*)&hl[(ty * 4 + r) * HS + k4];
#pragma unroll
      for (int j = 0; j < 4; ++j) {
        float4 bv = *(const float4*)&wl[(k4 + j) * 64 + tx * 4];
        const float* bp = (const float*)&bv;
#pragma unroll
        for (int r = 0; r < 4; ++r) {
          const float* ap = (const float*)&a[r];
#pragma unroll
          for (int c = 0; c < 4; ++c) acc[r][c] += ap[j] * bp[c];
        }
      }
    }
    __syncthreads();
  }

  // store
  if (FO == 64) {
#pragma unroll
    for (int r = 0; r < 4; ++r) {
      float4 v = make_float4(acc[r][0], acc[r][1], acc[r][2], acc[r][3]);
      *(float4*)&out[(size_t)(row0 + ty * 4 + r) * 64 + tx * 4] = v;
    }
  } else {
#pragma unroll
    for (int r = 0; r < 4; ++r)
#pragma unroll
      for (int c = 0; c < 4; ++c) {
        int col = tx * 4 + c;
        if (col < FO) out[(size_t)(row0 + ty * 4 + r) * FO + col] = acc[r][c];
      }
  }
}

// Pull aggregation: one wave per node, lane = feature (FO=64). Edge loop
// unrolled x4 with independent accumulators for latency hiding.
__global__ void agg_k(const float* __restrict__ support,
                      const int2* __restrict__ edata,
                      const int* __restrict__ off,
                      const float* __restrict__ bias,
                      const float* __restrict__ resid,
                      float* __restrict__ out,
                      int n, int do_relu) {
  int tid = blockIdx.x * blockDim.x + threadIdx.x;
  int wid = tid >> 6, lane = tid & 63;
  if (wid >= n) return;
  int e0 = off[wid], e1 = off[wid + 1];
  float a0 = 0.f, a1 = 0.f, a2 = 0.f, a3 = 0.f;
  int e = e0;
  for (; e + 4 <= e1; e += 4) {
    int2 p0 = edata[e], p1 = edata[e + 1], p2 = edata[e + 2], p3 = edata[e + 3];
    a0 += __int_as_float(p0.y) * support[(size_t)p0.x * 64 + lane];
    a1 += __int_as_float(p1.y) * support[(size_t)p1.x * 64 + lane];
    a2 += __int_as_float(p2.y) * support[(size_t)p2.x * 64 + lane];
    a3 += __int_as_float(p3.y) * support[(size_t)p3.x * 64 + lane];
  }
  for (; e < e1; ++e) {
    int2 p = edata[e];
    a0 += __int_as_float(p.y) * support[(size_t)p.x * 64 + lane];
  }
  float v = (a0 + a1) + (a2 + a3) + bias[lane];
  if (do_relu) v = fmaxf(v, 0.0f);
  if (resid) v += resid[(size_t)wid * 64 + lane];
  out[(size_t)wid * 64 + lane] = v;
}

// Final layer: FO=40 aggregation + bias + log_softmax, one wave per node.
__global__ void agg_final_k(const float* __restrict__ support,
                            const int2* __restrict__ edata,
                            const int* __restrict__ off,
                            const float* __restrict__ bias,
                            float* __restrict__ out, int n) {
  int tid = blockIdx.x * blockDim.x + threadIdx.x;
  int wid = tid >> 6, lane = tid & 63;
  if (wid >= n) return;
  int e0 = off[wid], e1 = off[wid + 1];
  float a0 = 0.f, a1 = 0.f;
  if (lane < NCLASS) {
    int e = e0;
    for (; e + 2 <= e1; e += 2) {
      int2 p0 = edata[e], p1 = edata[e + 1];
      a0 += __int_as_float(p0.y) * support[(size_t)p0.x * NCLASS + lane];
      a1 += __int_as_float(p1.y) * support[(size_t)p1.x * NCLASS + lane];
    }
    for (; e < e1; ++e) {
      int2 p = edata[e];
      a0 += __int_as_float(p.y) * support[(size_t)p.x * NCLASS + lane];
    }
    a0 += a1 + bias[lane];
  }
  float v = (lane < NCLASS) ? a0 : -INFINITY;
  float m = v;
#pragma unroll
  for (int d = 32; d; d >>= 1) m = fmaxf(m, __shfl_xor(m, d, 64));
  float ex = (lane < NCLASS) ? expf(v - m) : 0.0f;
  float s = ex;
#pragma unroll
  for (int d = 32; d; d >>= 1) s += __shfl_xor(s, d, 64);
  if (lane < NCLASS) out[(size_t)wid * NCLASS + lane] = (v - m) - logf(s);
}

extern "C" void kernel_launch(void* const* d_in, const int* in_sizes, int n_in,
                              void* d_out, int out_size, void* d_ws, size_t ws_size,
                              hipStream_t stream) {
  const float* x   = (const float*)d_in[0];
  const int*   src = (const int*)d_in[1];
  const int*   dst = (const int*)d_in[2];
  const float* ew  = (const float*)d_in[3];
  const float* W[7]; const float* b[7];
  for (int i = 0; i < 7; ++i) {
    W[i] = (const float*)d_in[4 + 2 * i];
    b[i] = (const float*)d_in[5 + 2 * i];
  }
  int N = in_sizes[0] / NFEAT;   // 65536
  int E = in_sizes[1];           // 1048576

  char* ws = (char*)d_ws;
  int*   off     = (int*)(ws + 0);                    // (N+1) ints
  int*   bsum    = (int*)(ws + (1ll << 20));          // 256 ints
  int*   cnt     = (int*)(ws + (2ll << 20));          // N ints
  int2*  edata   = (int2*)(ws + (4ll << 20));         // E int2 = 8MB
  float* support = (float*)(ws + (16ll << 20));       // N*64 f32 = 16MB
  float* hA      = (float*)(ws + (32ll << 20));       // 16MB
  float* hB      = (float*)(ws + (48ll << 20));       // 16MB

  // ---- build dst-CSR ----
  hipMemsetAsync(cnt, 0, (size_t)N * sizeof(int), stream);
  hist_k<<<(E + 255) / 256, 256, 0, stream>>>(dst, cnt, E);
  int nb = (N + 255) / 256;  // 256 blocks
  scan1_k<<<nb, 256, 0, stream>>>(cnt, off, bsum, N);
  scan2_k<<<1, 256, 0, stream>>>(bsum, nb);
  scan3_k<<<nb, 256, 0, stream>>>(off, bsum, N, E);
  hipMemsetAsync(cnt, 0, (size_t)N * sizeof(int), stream);
  fill_k<<<(E + 255) / 256, 256, 0, stream>>>(src, dst, ew, off, cnt, edata, E);

  int gb_gemm = N / 64;  // 1024 blocks, 64 rows each
  int gb_agg  = N / 4;   // 4 waves (nodes) per 256-thread block

  // L1: x[128] -> 64, relu
  gemm_k<128, 64><<<gb_gemm, 256, 0, stream>>>(x, W[0], support, N);
  agg_k<<<gb_agg, 256, 0, stream>>>(support, edata, off, b[0], nullptr, hA, N, 1);
  // L2
  gemm_k<64, 64><<<gb_gemm, 256, 0, stream>>>(hA, W[1], support, N);
  agg_k<<<gb_agg, 256, 0, stream>>>(support, edata, off, b[1], nullptr, hB, N, 1);
  // L3: + residual (h2 = hB)
  gemm_k<64, 64><<<gb_gemm, 256, 0, stream>>>(hB, W[2], support, N);
  agg_k<<<gb_agg, 256, 0, stream>>>(support, edata, off, b[2], hB, hA, N, 1);
  // L4: + residual (h3 = hA)
  gemm_k<64, 64><<<gb_gemm, 256, 0, stream>>>(hA, W[3], support, N);
  agg_k<<<gb_agg, 256, 0, stream>>>(support, edata, off, b[3], hA, hB, N, 1);
  // L5: + residual (h4 = hB)
  gemm_k<64, 64><<<gb_gemm, 256, 0, stream>>>(hB, W[4], support, N);
  agg_k<<<gb_agg, 256, 0, stream>>>(support, edata, off, b[4], hB, hA, N, 1);
  // L6
  gemm_k<64, 64><<<gb_gemm, 256, 0, stream>>>(hA, W[5], support, N);
  agg_k<<<gb_agg, 256, 0, stream>>>(support, edata, off, b[5], nullptr, hB, N, 1);
  // L7: 64 -> 40, + log_softmax
  gemm_k<64, 40><<<gb_gemm, 256, 0, stream>>>(hB, W[6], support, N);
  agg_final_k<<<gb_agg, 256, 0, stream>>>(support, edata, off, b[6], (float*)d_out, N);
}

// Round 3
// 545.390 us; speedup vs baseline: 2.4745x; 1.0815x over previous
//
#include <hip/hip_runtime.h>
#include <math.h>

// GCN: 7 graph-conv layers. N=65536 nodes, E=1048576 edges, feat 128->64(x6)->40.
// dst-CSR built once per call; per layer {register-blocked GEMM, pull-aggregate}.

constexpr int NFEAT = 128, NHID = 64, NCLASS = 40;

// Histogram + per-edge rank in one pass (rank write is coalesced).
__global__ void rank_k(const int* __restrict__ dst, int* __restrict__ cnt,
                       int* __restrict__ rank, int E) {
  int i = blockIdx.x * blockDim.x + threadIdx.x;
  if (i < E) rank[i] = atomicAdd(&cnt[dst[i]], 1);
}

__global__ void scan1_k(const int* __restrict__ cnt, int* __restrict__ off,
                        int* __restrict__ bsum, int n) {
  __shared__ int tmp[256];
  int tid = threadIdx.x;
  int i = blockIdx.x * 256 + tid;
  int v = (i < n) ? cnt[i] : 0;
  tmp[tid] = v;
  __syncthreads();
  for (int d = 1; d < 256; d <<= 1) {
    int t = (tid >= d) ? tmp[tid - d] : 0;
    __syncthreads();
    tmp[tid] += t;
    __syncthreads();
  }
  if (i < n) off[i] = tmp[tid] - v;  // exclusive
  if (tid == 255) bsum[blockIdx.x] = tmp[255];
}

__global__ void scan2_k(int* __restrict__ bsum, int nb) {
  __shared__ int tmp[256];
  int tid = threadIdx.x;
  int v = (tid < nb) ? bsum[tid] : 0;
  tmp[tid] = v;
  __syncthreads();
  for (int d = 1; d < 256; d <<= 1) {
    int t = (tid >= d) ? tmp[tid - d] : 0;
    __syncthreads();
    tmp[tid] += t;
    __syncthreads();
  }
  if (tid < nb) bsum[tid] = tmp[tid] - v;  // exclusive
}

__global__ void scan3_k(int* __restrict__ off, const int* __restrict__ bsum, int n, int E) {
  int i = blockIdx.x * blockDim.x + threadIdx.x;
  if (i < n) off[i] += bsum[i >> 8];
  if (i == 0) off[n] = E;
}

// Atomic-free scatter: pos = off[dst] + rank. Non-temporal store to avoid
// write-allocate on the random 8B scatter (R2 showed 64B HBM write per edge).
__global__ void fill_k(const int* __restrict__ src, const int* __restrict__ dst,
                       const float* __restrict__ w, const int* __restrict__ off,
                       const int* __restrict__ rank, int2* __restrict__ edata, int E) {
  int i = blockIdx.x * blockDim.x + threadIdx.x;
  if (i < E) {
    int pos = off[dst[i]] + rank[i];
    int2 v = make_int2(src[i], __float_as_int(w[i]));
    __builtin_nontemporal_store(*(const long long*)&v, (long long*)&edata[pos]);
  }
}

// Register-blocked GEMM: 64x64 output tile / 256-thread block, 4x4 per thread.
template<int FI, int FO>
__global__ __launch_bounds__(256) void gemm_k(const float* __restrict__ h,
                                              const float* __restrict__ W,
                                              float* __restrict__ out, int n) {
  constexpr int HS = 68;            // h_lds row stride (floats), 16B-aligned, pad 4
  __shared__ float hl[64 * HS];     // 17408 B
  __shared__ float wl[64 * 64];     // 16384 B
  int tid = threadIdx.x;
  int row0 = blockIdx.x * 64;
  int tx = tid & 15, ty = tid >> 4;   // col group, row group

  float acc[4][4] = {};

  for (int kc = 0; kc < FI; kc += 64) {
    {
      const float* hb = h + (size_t)row0 * FI + kc;
      for (int i = tid; i < 64 * 16; i += 256) {
        int r = i >> 4, kk = (i & 15) << 2;
        float4 v = *(const float4*)(hb + (size_t)r * FI + kk);
        *(float4*)&hl[r * HS + kk] = v;
      }
    }
    if (FO == 64) {
      const float4* Wb = (const float4*)(W + (size_t)kc * 64);
      for (int i = tid; i < 64 * 16; i += 256) ((float4*)wl)[i] = Wb[i];
    } else {
      for (int i = tid; i < 64 * 64; i += 256) wl[i] = 0.0f;
      __syncthreads();
      for (int i = tid; i < 64 * FO; i += 256)
        wl[(i / FO) * 64 + (i % FO)] = W[(size_t)(kc + i / FO) * FO + (i % FO)];
    }
    __syncthreads();

    for (int k4 = 0; k4 < 64; k4 += 4) {
      float4 a[4];
#pragma unroll
      for (int r = 0; r < 4; ++r)
        a[r] = *(const float4*)&hl[(ty * 4 + r) * HS + k4];
#pragma unroll
      for (int j = 0; j < 4; ++j) {
        float4 bv = *(const float4*)&wl[(k4 + j) * 64 + tx * 4];
        const float* bp = (const float*)&bv;
#pragma unroll
        for (int r = 0; r < 4; ++r) {
          const float* ap = (const float*)&a[r];
#pragma unroll
          for (int c = 0; c < 4; ++c) acc[r][c] += ap[j] * bp[c];
        }
      }
    }
    __syncthreads();
  }

  if (FO == 64) {
#pragma unroll
    for (int r = 0; r < 4; ++r) {
      float4 v = make_float4(acc[r][0], acc[r][1], acc[r][2], acc[r][3]);
      *(float4*)&out[(size_t)(row0 + ty * 4 + r) * 64 + tx * 4] = v;
    }
  } else {
#pragma unroll
    for (int r = 0; r < 4; ++r)
#pragma unroll
      for (int c = 0; c < 4; ++c) {
        int col = tx * 4 + c;
        if (col < FO) out[(size_t)(row0 + ty * 4 + r) * FO + col] = acc[r][c];
      }
  }
}

// Pull aggregation: one wave per node, lane = feature (FO=64).
// 8 independent accumulators -> 8 gathers in flight per wave.
__global__ void agg_k(const float* __restrict__ support,
                      const int2* __restrict__ edata,
                      const int* __restrict__ off,
                      const float* __restrict__ bias,
                      const float* __restrict__ resid,
                      float* __restrict__ out,
                      int n, int do_relu) {
  int tid = blockIdx.x * blockDim.x + threadIdx.x;
  int wid = tid >> 6, lane = tid & 63;
  if (wid >= n) return;
  int e0 = off[wid], e1 = off[wid + 1];
  float bv = bias[lane];
  float rv = resid ? resid[(size_t)wid * 64 + lane] : 0.0f;
  float a[8] = {};
  int e = e0;
  for (; e + 8 <= e1; e += 8) {
    int2 p[8];
#pragma unroll
    for (int j = 0; j < 8; ++j) p[j] = edata[e + j];
#pragma unroll
    for (int j = 0; j < 8; ++j)
      a[j] += __int_as_float(p[j].y) * support[(size_t)p[j].x * 64 + lane];
  }
  for (; e < e1; ++e) {
    int2 p = edata[e];
    a[0] += __int_as_float(p.y) * support[(size_t)p.x * 64 + lane];
  }
  float v = ((a[0] + a[1]) + (a[2] + a[3])) + ((a[4] + a[5]) + (a[6] + a[7])) + bv;
  if (do_relu) v = fmaxf(v, 0.0f);
  v += rv;
  out[(size_t)wid * 64 + lane] = v;
}

// Final layer: FO=40 aggregation + bias + log_softmax, one wave per node.
__global__ void agg_final_k(const float* __restrict__ support,
                            const int2* __restrict__ edata,
                            const int* __restrict__ off,
                            const float* __restrict__ bias,
                            float* __restrict__ out, int n) {
  int tid = blockIdx.x * blockDim.x + threadIdx.x;
  int wid = tid >> 6, lane = tid & 63;
  if (wid >= n) return;
  int e0 = off[wid], e1 = off[wid + 1];
  float a0 = 0.f, a1 = 0.f, a2 = 0.f, a3 = 0.f;
  if (lane < NCLASS) {
    int e = e0;
    for (; e + 4 <= e1; e += 4) {
      int2 p0 = edata[e], p1 = edata[e + 1], p2 = edata[e + 2], p3 = edata[e + 3];
      a0 += __int_as_float(p0.y) * support[(size_t)p0.x * NCLASS + lane];
      a1 += __int_as_float(p1.y) * support[(size_t)p1.x * NCLASS + lane];
      a2 += __int_as_float(p2.y) * support[(size_t)p2.x * NCLASS + lane];
      a3 += __int_as_float(p3.y) * support[(size_t)p3.x * NCLASS + lane];
    }
    for (; e < e1; ++e) {
      int2 p = edata[e];
      a0 += __int_as_float(p.y) * support[(size_t)p.x * NCLASS + lane];
    }
    a0 += (a1 + a2) + a3 + bias[lane];
  }
  float v = (lane < NCLASS) ? a0 : -INFINITY;
  float m = v;
#pragma unroll
  for (int d = 32; d; d >>= 1) m = fmaxf(m, __shfl_xor(m, d, 64));
  float ex = (lane < NCLASS) ? expf(v - m) : 0.0f;
  float s = ex;
#pragma unroll
  for (int d = 32; d; d >>= 1) s += __shfl_xor(s, d, 64);
  if (lane < NCLASS) out[(size_t)wid * NCLASS + lane] = (v - m) - logf(s);
}

extern "C" void kernel_launch(void* const* d_in, const int* in_sizes, int n_in,
                              void* d_out, int out_size, void* d_ws, size_t ws_size,
                              hipStream_t stream) {
  const float* x   = (const float*)d_in[0];
  const int*   src = (const int*)d_in[1];
  const int*   dst = (const int*)d_in[2];
  const float* ew  = (const float*)d_in[3];
  const float* W[7]; const float* b[7];
  for (int i = 0; i < 7; ++i) {
    W[i] = (const float*)d_in[4 + 2 * i];
    b[i] = (const float*)d_in[5 + 2 * i];
  }
  int N = in_sizes[0] / NFEAT;   // 65536
  int E = in_sizes[1];           // 1048576

  char* ws = (char*)d_ws;
  int*   off     = (int*)(ws + 0);                    // (N+1) ints
  int*   bsum    = (int*)(ws + (1ll << 20));          // 256 ints
  int*   cnt     = (int*)(ws + (2ll << 20));          // N ints
  int2*  edata   = (int2*)(ws + (4ll << 20));         // E int2 = 8MB  [4,12)MB
  int*   rank    = (int*)(ws + (12ll << 20));         // E ints = 4MB  [12,16)MB
  float* support = (float*)(ws + (16ll << 20));       // N*64 f32 = 16MB
  float* hA      = (float*)(ws + (32ll << 20));       // 16MB
  float* hB      = (float*)(ws + (48ll << 20));       // 16MB

  // ---- build dst-CSR ----
  hipMemsetAsync(cnt, 0, (size_t)N * sizeof(int), stream);
  rank_k<<<(E + 255) / 256, 256, 0, stream>>>(dst, cnt, rank, E);
  int nb = (N + 255) / 256;  // 256 blocks
  scan1_k<<<nb, 256, 0, stream>>>(cnt, off, bsum, N);
  scan2_k<<<1, 256, 0, stream>>>(bsum, nb);
  scan3_k<<<nb, 256, 0, stream>>>(off, bsum, N, E);
  fill_k<<<(E + 255) / 256, 256, 0, stream>>>(src, dst, ew, off, rank, edata, E);

  int gb_gemm = N / 64;  // 1024 blocks, 64 rows each
  int gb_agg  = N / 4;   // 4 waves (nodes) per 256-thread block

  // L1: x[128] -> 64, relu
  gemm_k<128, 64><<<gb_gemm, 256, 0, stream>>>(x, W[0], support, N);
  agg_k<<<gb_agg, 256, 0, stream>>>(support, edata, off, b[0], nullptr, hA, N, 1);
  // L2
  gemm_k<64, 64><<<gb_gemm, 256, 0, stream>>>(hA, W[1], support, N);
  agg_k<<<gb_agg, 256, 0, stream>>>(support, edata, off, b[1], nullptr, hB, N, 1);
  // L3: + residual (h2 = hB)
  gemm_k<64, 64><<<gb_gemm, 256, 0, stream>>>(hB, W[2], support, N);
  agg_k<<<gb_agg, 256, 0, stream>>>(support, edata, off, b[2], hB, hA, N, 1);
  // L4: + residual (h3 = hA)
  gemm_k<64, 64><<<gb_gemm, 256, 0, stream>>>(hA, W[3], support, N);
  agg_k<<<gb_agg, 256, 0, stream>>>(support, edata, off, b[3], hA, hB, N, 1);
  // L5: + residual (h4 = hB)
  gemm_k<64, 64><<<gb_gemm, 256, 0, stream>>>(hB, W[4], support, N);
  agg_k<<<gb_agg, 256, 0, stream>>>(support, edata, off, b[4], hB, hA, N, 1);
  // L6
  gemm_k<64, 64><<<gb_gemm, 256, 0, stream>>>(hA, W[5], support, N);
  agg_k<<<gb_agg, 256, 0, stream>>>(support, edata, off, b[5], nullptr, hB, N, 1);
  // L7: 64 -> 40, + log_softmax
  gemm_k<64, 40><<<gb_gemm, 256, 0, stream>>>(hB, W[6], support, N);
  agg_final_k<<<gb_agg, 256, 0, stream>>>(support, edata, off, b[6], (float*)d_out, N);
}

// Round 4
// 512.521 us; speedup vs baseline: 2.6331x; 1.0641x over previous
//
#include <hip/hip_runtime.h>
#include <math.h>

// GCN: 7 graph-conv layers. N=65536 nodes, E=1048576 edges, feat 128->64(x6)->40.
// dst-CSR once per call; per layer {register-blocked GEMM -> bf16 support,
// pull-aggregate with f32 accumulation}.

constexpr int NFEAT = 128, NHID = 64, NCLASS = 40;

typedef unsigned short ushort_t;

__device__ inline float bf2f(ushort_t u) {
  union { unsigned int i; float f; } v; v.i = ((unsigned int)u) << 16; return v.f;
}
__device__ inline ushort_t f2bf(float f) {  // round-to-nearest-even
  union { float f; unsigned int i; } v; v.f = f;
  unsigned int lsb = (v.i >> 16) & 1u;
  v.i += 0x7fffu + lsb;
  return (ushort_t)(v.i >> 16);
}

// Histogram + per-edge rank in one pass (rank write is coalesced).
__global__ void rank_k(const int* __restrict__ dst, int* __restrict__ cnt,
                       int* __restrict__ rank, int E) {
  int i = blockIdx.x * blockDim.x + threadIdx.x;
  if (i < E) rank[i] = atomicAdd(&cnt[dst[i]], 1);
}

__global__ void scan1_k(const int* __restrict__ cnt, int* __restrict__ off,
                        int* __restrict__ bsum, int n) {
  __shared__ int tmp[256];
  int tid = threadIdx.x;
  int i = blockIdx.x * 256 + tid;
  int v = (i < n) ? cnt[i] : 0;
  tmp[tid] = v;
  __syncthreads();
  for (int d = 1; d < 256; d <<= 1) {
    int t = (tid >= d) ? tmp[tid - d] : 0;
    __syncthreads();
    tmp[tid] += t;
    __syncthreads();
  }
  if (i < n) off[i] = tmp[tid] - v;  // exclusive
  if (tid == 255) bsum[blockIdx.x] = tmp[255];
}

__global__ void scan2_k(int* __restrict__ bsum, int nb) {
  __shared__ int tmp[256];
  int tid = threadIdx.x;
  int v = (tid < nb) ? bsum[tid] : 0;
  tmp[tid] = v;
  __syncthreads();
  for (int d = 1; d < 256; d <<= 1) {
    int t = (tid >= d) ? tmp[tid - d] : 0;
    __syncthreads();
    tmp[tid] += t;
    __syncthreads();
  }
  if (tid < nb) bsum[tid] = tmp[tid] - v;  // exclusive
}

__global__ void scan3_k(int* __restrict__ off, const int* __restrict__ bsum, int n, int E) {
  int i = blockIdx.x * blockDim.x + threadIdx.x;
  if (i < n) off[i] += bsum[i >> 8];
  if (i == 0) off[n] = E;
}

// Atomic-free scatter: pos = off[dst] + rank, non-temporal 8B store.
__global__ void fill_k(const int* __restrict__ src, const int* __restrict__ dst,
                       const float* __restrict__ w, const int* __restrict__ off,
                       const int* __restrict__ rank, int2* __restrict__ edata, int E) {
  int i = blockIdx.x * blockDim.x + threadIdx.x;
  if (i < E) {
    int pos = off[dst[i]] + rank[i];
    int2 v = make_int2(src[i], __float_as_int(w[i]));
    __builtin_nontemporal_store(*(const long long*)&v, (long long*)&edata[pos]);
  }
}

// Register-blocked GEMM: 64x64 tile / 256-thread block, 4x4 per thread.
// Output written as bf16 (support tables).
template<int FI, int FO>
__global__ __launch_bounds__(256) void gemm_k(const float* __restrict__ h,
                                              const float* __restrict__ W,
                                              ushort_t* __restrict__ out, int n) {
  constexpr int HS = 68;            // h_lds row stride, pad 4
  __shared__ float hl[64 * HS];     // 17408 B
  __shared__ float wl[64 * 64];     // 16384 B
  int tid = threadIdx.x;
  int row0 = blockIdx.x * 64;
  int tx = tid & 15, ty = tid >> 4;

  float acc[4][4] = {};

  for (int kc = 0; kc < FI; kc += 64) {
    {
      const float* hb = h + (size_t)row0 * FI + kc;
      for (int i = tid; i < 64 * 16; i += 256) {
        int r = i >> 4, kk = (i & 15) << 2;
        float4 v = *(const float4*)(hb + (size_t)r * FI + kk);
        *(float4*)&hl[r * HS + kk] = v;
      }
    }
    if (FO == 64) {
      const float4* Wb = (const float4*)(W + (size_t)kc * 64);
      for (int i = tid; i < 64 * 16; i += 256) ((float4*)wl)[i] = Wb[i];
    } else {
      for (int i = tid; i < 64 * 64; i += 256) wl[i] = 0.0f;
      __syncthreads();
      for (int i = tid; i < 64 * FO; i += 256)
        wl[(i / FO) * 64 + (i % FO)] = W[(size_t)(kc + i / FO) * FO + (i % FO)];
    }
    __syncthreads();

    for (int k4 = 0; k4 < 64; k4 += 4) {
      float4 a[4];
#pragma unroll
      for (int r = 0; r < 4; ++r)
        a[r] = *(const float4*)&hl[(ty * 4 + r) * HS + k4];
#pragma unroll
      for (int j = 0; j < 4; ++j) {
        float4 bv = *(const float4*)&wl[(k4 + j) * 64 + tx * 4];
        const float* bp = (const float*)&bv;
#pragma unroll
        for (int r = 0; r < 4; ++r) {
          const float* ap = (const float*)&a[r];
#pragma unroll
          for (int c = 0; c < 4; ++c) acc[r][c] += ap[j] * bp[c];
        }
      }
    }
    __syncthreads();
  }

  if (FO == 64) {
#pragma unroll
    for (int r = 0; r < 4; ++r) {
      ushort_t pk[4];
#pragma unroll
      for (int c = 0; c < 4; ++c) pk[c] = f2bf(acc[r][c]);
      *(ushort4*)&out[(size_t)(row0 + ty * 4 + r) * 64 + tx * 4] =
          make_ushort4(pk[0], pk[1], pk[2], pk[3]);
    }
  } else {
#pragma unroll
    for (int r = 0; r < 4; ++r)
#pragma unroll
      for (int c = 0; c < 4; ++c) {
        int col = tx * 4 + c;
        if (col < FO) out[(size_t)(row0 + ty * 4 + r) * FO + col] = f2bf(acc[r][c]);
      }
  }
}

// Pull aggregation: one wave per node, lane = feature. bf16 support rows
// (128 B), f32 accumulate, 8 gathers in flight.
__global__ void agg_k(const ushort_t* __restrict__ support,
                      const int2* __restrict__ edata,
                      const int* __restrict__ off,
                      const float* __restrict__ bias,
                      const float* __restrict__ resid,
                      float* __restrict__ out,
                      int n, int do_relu) {
  int tid = blockIdx.x * blockDim.x + threadIdx.x;
  int wid = tid >> 6, lane = tid & 63;
  if (wid >= n) return;
  int e0 = off[wid], e1 = off[wid + 1];
  float bv = bias[lane];
  float rv = resid ? resid[(size_t)wid * 64 + lane] : 0.0f;
  float a[8] = {};
  int e = e0;
  for (; e + 8 <= e1; e += 8) {
    int2 p[8];
#pragma unroll
    for (int j = 0; j < 8; ++j) p[j] = edata[e + j];
    ushort_t s[8];
#pragma unroll
    for (int j = 0; j < 8; ++j) s[j] = support[(size_t)p[j].x * 64 + lane];
#pragma unroll
    for (int j = 0; j < 8; ++j) a[j] += __int_as_float(p[j].y) * bf2f(s[j]);
  }
  for (; e < e1; ++e) {
    int2 p = edata[e];
    a[0] += __int_as_float(p.y) * bf2f(support[(size_t)p.x * 64 + lane]);
  }
  float v = ((a[0] + a[1]) + (a[2] + a[3])) + ((a[4] + a[5]) + (a[6] + a[7])) + bv;
  if (do_relu) v = fmaxf(v, 0.0f);
  v += rv;
  out[(size_t)wid * 64 + lane] = v;
}

// Final layer: FO=40 bf16 aggregation + bias + log_softmax, one wave per node.
__global__ void agg_final_k(const ushort_t* __restrict__ support,
                            const int2* __restrict__ edata,
                            const int* __restrict__ off,
                            const float* __restrict__ bias,
                            float* __restrict__ out, int n) {
  int tid = blockIdx.x * blockDim.x + threadIdx.x;
  int wid = tid >> 6, lane = tid & 63;
  if (wid >= n) return;
  int e0 = off[wid], e1 = off[wid + 1];
  float a0 = 0.f, a1 = 0.f, a2 = 0.f, a3 = 0.f;
  if (lane < NCLASS) {
    int e = e0;
    for (; e + 4 <= e1; e += 4) {
      int2 p0 = edata[e], p1 = edata[e + 1], p2 = edata[e + 2], p3 = edata[e + 3];
      a0 += __int_as_float(p0.y) * bf2f(support[(size_t)p0.x * NCLASS + lane]);
      a1 += __int_as_float(p1.y) * bf2f(support[(size_t)p1.x * NCLASS + lane]);
      a2 += __int_as_float(p2.y) * bf2f(support[(size_t)p2.x * NCLASS + lane]);
      a3 += __int_as_float(p3.y) * bf2f(support[(size_t)p3.x * NCLASS + lane]);
    }
    for (; e < e1; ++e) {
      int2 p = edata[e];
      a0 += __int_as_float(p.y) * bf2f(support[(size_t)p.x * NCLASS + lane]);
    }
    a0 += (a1 + a2) + a3 + bias[lane];
  }
  float v = (lane < NCLASS) ? a0 : -INFINITY;
  float m = v;
#pragma unroll
  for (int d = 32; d; d >>= 1) m = fmaxf(m, __shfl_xor(m, d, 64));
  float ex = (lane < NCLASS) ? expf(v - m) : 0.0f;
  float s = ex;
#pragma unroll
  for (int d = 32; d; d >>= 1) s += __shfl_xor(s, d, 64);
  if (lane < NCLASS) out[(size_t)wid * NCLASS + lane] = (v - m) - logf(s);
}

extern "C" void kernel_launch(void* const* d_in, const int* in_sizes, int n_in,
                              void* d_out, int out_size, void* d_ws, size_t ws_size,
                              hipStream_t stream) {
  const float* x   = (const float*)d_in[0];
  const int*   src = (const int*)d_in[1];
  const int*   dst = (const int*)d_in[2];
  const float* ew  = (const float*)d_in[3];
  const float* W[7]; const float* b[7];
  for (int i = 0; i < 7; ++i) {
    W[i] = (const float*)d_in[4 + 2 * i];
    b[i] = (const float*)d_in[5 + 2 * i];
  }
  int N = in_sizes[0] / NFEAT;   // 65536
  int E = in_sizes[1];           // 1048576

  char* ws = (char*)d_ws;
  int*      off     = (int*)(ws + 0);                 // (N+1) ints
  int*      bsum    = (int*)(ws + (1ll << 20));       // 256 ints
  int*      cnt     = (int*)(ws + (2ll << 20));       // N ints
  int2*     edata   = (int2*)(ws + (4ll << 20));      // E int2 = 8MB  [4,12)
  int*      rank    = (int*)(ws + (12ll << 20));      // E ints = 4MB  [12,16)
  ushort_t* support = (ushort_t*)(ws + (16ll << 20)); // N*64 bf16 = 8MB [16,24)
  float*    hA      = (float*)(ws + (32ll << 20));    // 16MB
  float*    hB      = (float*)(ws + (48ll << 20));    // 16MB

  // ---- build dst-CSR ----
  hipMemsetAsync(cnt, 0, (size_t)N * sizeof(int), stream);
  rank_k<<<(E + 255) / 256, 256, 0, stream>>>(dst, cnt, rank, E);
  int nb = (N + 255) / 256;  // 256 blocks
  scan1_k<<<nb, 256, 0, stream>>>(cnt, off, bsum, N);
  scan2_k<<<1, 256, 0, stream>>>(bsum, nb);
  scan3_k<<<nb, 256, 0, stream>>>(off, bsum, N, E);
  fill_k<<<(E + 255) / 256, 256, 0, stream>>>(src, dst, ew, off, rank, edata, E);

  int gb_gemm = N / 64;  // 1024 blocks
  int gb_agg  = N / 4;   // 4 waves per 256-thread block

  // L1: x[128] -> 64, relu
  gemm_k<128, 64><<<gb_gemm, 256, 0, stream>>>(x, W[0], support, N);
  agg_k<<<gb_agg, 256, 0, stream>>>(support, edata, off, b[0], nullptr, hA, N, 1);
  // L2
  gemm_k<64, 64><<<gb_gemm, 256, 0, stream>>>(hA, W[1], support, N);
  agg_k<<<gb_agg, 256, 0, stream>>>(support, edata, off, b[1], nullptr, hB, N, 1);
  // L3: + residual (h2 = hB)
  gemm_k<64, 64><<<gb_gemm, 256, 0, stream>>>(hB, W[2], support, N);
  agg_k<<<gb_agg, 256, 0, stream>>>(support, edata, off, b[2], hB, hA, N, 1);
  // L4: + residual (h3 = hA)
  gemm_k<64, 64><<<gb_gemm, 256, 0, stream>>>(hA, W[3], support, N);
  agg_k<<<gb_agg, 256, 0, stream>>>(support, edata, off, b[3], hA, hB, N, 1);
  // L5: + residual (h4 = hB)
  gemm_k<64, 64><<<gb_gemm, 256, 0, stream>>>(hB, W[4], support, N);
  agg_k<<<gb_agg, 256, 0, stream>>>(support, edata, off, b[4], hB, hA, N, 1);
  // L6
  gemm_k<64, 64><<<gb_gemm, 256, 0, stream>>>(hA, W[5], support, N);
  agg_k<<<gb_agg, 256, 0, stream>>>(support, edata, off, b[5], nullptr, hB, N, 1);
  // L7: 64 -> 40, + log_softmax
  gemm_k<64, 40><<<gb_gemm, 256, 0, stream>>>(hB, W[6], support, N);
  agg_final_k<<<gb_agg, 256, 0, stream>>>(support, edata, off, b[6], (float*)d_out, N);
}

// Round 5
// 459.989 us; speedup vs baseline: 2.9339x; 1.1142x over previous
//
#include <hip/hip_runtime.h>
#include <math.h>

// GCN: 7 graph-conv layers. N=65536 nodes, E=1048576 edges, feat 128->64(x6)->40.
// dst-CSR once per call; per layer {register-blocked GEMM -> bf16 support,
// pull-aggregate: 2 edges/gather-instr (half-wave split), f32 accumulation}.

constexpr int NFEAT = 128, NHID = 64, NCLASS = 40;

typedef unsigned short ushort_t;

__device__ inline float bf2f(ushort_t u) {
  union { unsigned int i; float f; } v; v.i = ((unsigned int)u) << 16; return v.f;
}
__device__ inline ushort_t f2bf(float f) {  // round-to-nearest-even
  union { float f; unsigned int i; } v; v.f = f;
  unsigned int lsb = (v.i >> 16) & 1u;
  v.i += 0x7fffu + lsb;
  return (ushort_t)(v.i >> 16);
}

// Histogram + per-edge rank in one pass (rank write is coalesced).
__global__ void rank_k(const int* __restrict__ dst, int* __restrict__ cnt,
                       int* __restrict__ rank, int E) {
  int i = blockIdx.x * blockDim.x + threadIdx.x;
  if (i < E) rank[i] = atomicAdd(&cnt[dst[i]], 1);
}

__global__ void scan1_k(const int* __restrict__ cnt, int* __restrict__ off,
                        int* __restrict__ bsum, int n) {
  __shared__ int tmp[256];
  int tid = threadIdx.x;
  int i = blockIdx.x * 256 + tid;
  int v = (i < n) ? cnt[i] : 0;
  tmp[tid] = v;
  __syncthreads();
  for (int d = 1; d < 256; d <<= 1) {
    int t = (tid >= d) ? tmp[tid - d] : 0;
    __syncthreads();
    tmp[tid] += t;
    __syncthreads();
  }
  if (i < n) off[i] = tmp[tid] - v;  // exclusive
  if (tid == 255) bsum[blockIdx.x] = tmp[255];
}

__global__ void scan2_k(int* __restrict__ bsum, int nb) {
  __shared__ int tmp[256];
  int tid = threadIdx.x;
  int v = (tid < nb) ? bsum[tid] : 0;
  tmp[tid] = v;
  __syncthreads();
  for (int d = 1; d < 256; d <<= 1) {
    int t = (tid >= d) ? tmp[tid - d] : 0;
    __syncthreads();
    tmp[tid] += t;
    __syncthreads();
  }
  if (tid < nb) bsum[tid] = tmp[tid] - v;  // exclusive
}

__global__ void scan3_k(int* __restrict__ off, const int* __restrict__ bsum, int n, int E) {
  int i = blockIdx.x * blockDim.x + threadIdx.x;
  if (i < n) off[i] += bsum[i >> 8];
  if (i == 0) off[n] = E;
}

// Atomic-free scatter: pos = off[dst] + rank, non-temporal 8B store.
__global__ void fill_k(const int* __restrict__ src, const int* __restrict__ dst,
                       const float* __restrict__ w, const int* __restrict__ off,
                       const int* __restrict__ rank, int2* __restrict__ edata, int E) {
  int i = blockIdx.x * blockDim.x + threadIdx.x;
  if (i < E) {
    int pos = off[dst[i]] + rank[i];
    int2 v = make_int2(src[i], __float_as_int(w[i]));
    __builtin_nontemporal_store(*(const long long*)&v, (long long*)&edata[pos]);
  }
}

// Register-blocked GEMM: 64x64 tile / 256-thread block, 4x4 per thread.
// Output written as bf16 (support tables).
template<int FI, int FO>
__global__ __launch_bounds__(256) void gemm_k(const float* __restrict__ h,
                                              const float* __restrict__ W,
                                              ushort_t* __restrict__ out, int n) {
  constexpr int HS = 68;            // h_lds row stride, pad 4
  __shared__ float hl[64 * HS];     // 17408 B
  __shared__ float wl[64 * 64];     // 16384 B
  int tid = threadIdx.x;
  int row0 = blockIdx.x * 64;
  int tx = tid & 15, ty = tid >> 4;

  float acc[4][4] = {};

  for (int kc = 0; kc < FI; kc += 64) {
    {
      const float* hb = h + (size_t)row0 * FI + kc;
      for (int i = tid; i < 64 * 16; i += 256) {
        int r = i >> 4, kk = (i & 15) << 2;
        float4 v = *(const float4*)(hb + (size_t)r * FI + kk);
        *(float4*)&hl[r * HS + kk] = v;
      }
    }
    if (FO == 64) {
      const float4* Wb = (const float4*)(W + (size_t)kc * 64);
      for (int i = tid; i < 64 * 16; i += 256) ((float4*)wl)[i] = Wb[i];
    } else {
      for (int i = tid; i < 64 * 64; i += 256) wl[i] = 0.0f;
      __syncthreads();
      for (int i = tid; i < 64 * FO; i += 256)
        wl[(i / FO) * 64 + (i % FO)] = W[(size_t)(kc + i / FO) * FO + (i % FO)];
    }
    __syncthreads();

    for (int k4 = 0; k4 < 64; k4 += 4) {
      float4 a[4];
#pragma unroll
      for (int r = 0; r < 4; ++r)
        a[r] = *(const float4*)&hl[(ty * 4 + r) * HS + k4];
#pragma unroll
      for (int j = 0; j < 4; ++j) {
        float4 bv = *(const float4*)&wl[(k4 + j) * 64 + tx * 4];
        const float* bp = (const float*)&bv;
#pragma unroll
        for (int r = 0; r < 4; ++r) {
          const float* ap = (const float*)&a[r];
#pragma unroll
          for (int c = 0; c < 4; ++c) acc[r][c] += ap[j] * bp[c];
        }
      }
    }
    __syncthreads();
  }

  if (FO == 64) {
#pragma unroll
    for (int r = 0; r < 4; ++r) {
      ushort_t pk[4];
#pragma unroll
      for (int c = 0; c < 4; ++c) pk[c] = f2bf(acc[r][c]);
      *(ushort4*)&out[(size_t)(row0 + ty * 4 + r) * 64 + tx * 4] =
          make_ushort4(pk[0], pk[1], pk[2], pk[3]);
    }
  } else {
#pragma unroll
    for (int r = 0; r < 4; ++r)
#pragma unroll
      for (int c = 0; c < 4; ++c) {
        int col = tx * 4 + c;
        if (col < FO) out[(size_t)(row0 + ty * 4 + r) * FO + col] = f2bf(acc[r][c]);
      }
  }
}

// Pull aggregation: one wave per node. Lane = (half, featpair): lanes 0-31
// handle even edges, 32-63 odd edges; each lane loads 2 bf16 feats as one
// uint -> 2 edges per gather instruction, 16 edges in flight per iteration.
// OOB pairs clamp the index and zero the weight (keeps tail ILP).
__global__ void agg_k(const ushort_t* __restrict__ support,
                      const int2* __restrict__ edata,
                      const int* __restrict__ off,
                      const float* __restrict__ bias,
                      const float* __restrict__ resid,
                      float* __restrict__ out,
                      int n, int do_relu) {
  int tid = blockIdx.x * blockDim.x + threadIdx.x;
  int wid = tid >> 6, lane = tid & 63;
  if (wid >= n) return;
  int half = lane >> 5;   // which edge of the pair
  int hl   = lane & 31;   // feature pair (feats 2hl, 2hl+1)
  int e0 = off[wid], e1 = off[wid + 1];

  float ax[8] = {}, ay[8] = {};
  for (int e = e0; e < e1; e += 16) {
    int2 ed[8];
#pragma unroll
    for (int j = 0; j < 8; ++j) {
      int ee = e + 2 * j + half;
      ed[j] = edata[ee < e1 ? ee : e1 - 1];
    }
    unsigned int u[8];
#pragma unroll
    for (int j = 0; j < 8; ++j)
      u[j] = *(const unsigned int*)&support[(size_t)ed[j].x * 64 + hl * 2];
#pragma unroll
    for (int j = 0; j < 8; ++j) {
      int ee = e + 2 * j + half;
      float w = (ee < e1) ? __int_as_float(ed[j].y) : 0.0f;
      ax[j] += w * __int_as_float(u[j] << 16);
      ay[j] += w * __int_as_float(u[j] & 0xffff0000u);
    }
  }
  float sx = ((ax[0] + ax[1]) + (ax[2] + ax[3])) + ((ax[4] + ax[5]) + (ax[6] + ax[7]));
  float sy = ((ay[0] + ay[1]) + (ay[2] + ay[3])) + ((ay[4] + ay[5]) + (ay[6] + ay[7]));
  sx += __shfl_xor(sx, 32, 64);
  sy += __shfl_xor(sy, 32, 64);
  if (half == 0) {
    float2 bv = *(const float2*)&bias[hl * 2];
    float vx = sx + bv.x, vy = sy + bv.y;
    if (do_relu) { vx = fmaxf(vx, 0.0f); vy = fmaxf(vy, 0.0f); }
    if (resid) {
      float2 r = *(const float2*)&resid[(size_t)wid * 64 + hl * 2];
      vx += r.x; vy += r.y;
    }
    *(float2*)&out[(size_t)wid * 64 + hl * 2] = make_float2(vx, vy);
  }
}

// Final layer: FO=40, same packed scheme (feat pairs 0..19 valid), then
// bias + log_softmax over 40 classes via 64-lane butterflies.
__global__ void agg_final_k(const ushort_t* __restrict__ support,
                            const int2* __restrict__ edata,
                            const int* __restrict__ off,
                            const float* __restrict__ bias,
                            float* __restrict__ out, int n) {
  int tid = blockIdx.x * blockDim.x + threadIdx.x;
  int wid = tid >> 6, lane = tid & 63;
  if (wid >= n) return;
  int half = lane >> 5;
  int hl   = lane & 31;
  int col  = (hl < 20 ? hl : 0) * 2;   // clamp to stay in-row
  int e0 = off[wid], e1 = off[wid + 1];

  float ax[8] = {}, ay[8] = {};
  for (int e = e0; e < e1; e += 16) {
    int2 ed[8];
#pragma unroll
    for (int j = 0; j < 8; ++j) {
      int ee = e + 2 * j + half;
      ed[j] = edata[ee < e1 ? ee : e1 - 1];
    }
    unsigned int u[8];
#pragma unroll
    for (int j = 0; j < 8; ++j)
      u[j] = *(const unsigned int*)&support[(size_t)ed[j].x * NCLASS + col];
#pragma unroll
    for (int j = 0; j < 8; ++j) {
      int ee = e + 2 * j + half;
      float w = (ee < e1) ? __int_as_float(ed[j].y) : 0.0f;
      ax[j] += w * __int_as_float(u[j] << 16);
      ay[j] += w * __int_as_float(u[j] & 0xffff0000u);
    }
  }
  float sx = ((ax[0] + ax[1]) + (ax[2] + ax[3])) + ((ax[4] + ax[5]) + (ax[6] + ax[7]));
  float sy = ((ay[0] + ay[1]) + (ay[2] + ay[3])) + ((ay[4] + ay[5]) + (ay[6] + ay[7]));
  sx += __shfl_xor(sx, 32, 64);
  sy += __shfl_xor(sy, 32, 64);
  float2 bv = *(const float2*)&bias[col];
  float vx = sx + bv.x, vy = sy + bv.y;

  bool valid = (hl < 20);
  float m = valid ? fmaxf(vx, vy) : -INFINITY;
#pragma unroll
  for (int d = 32; d; d >>= 1) m = fmaxf(m, __shfl_xor(m, d, 64));
  float ex = valid ? (expf(vx - m) + expf(vy - m)) : 0.0f;
  float s = ex;
#pragma unroll
  for (int d = 32; d; d >>= 1) s += __shfl_xor(s, d, 64);
  float ls = logf(s);
  if (half == 0 && valid)
    *(float2*)&out[(size_t)wid * NCLASS + hl * 2] = make_float2(vx - m - ls, vy - m - ls);
}

extern "C" void kernel_launch(void* const* d_in, const int* in_sizes, int n_in,
                              void* d_out, int out_size, void* d_ws, size_t ws_size,
                              hipStream_t stream) {
  const float* x   = (const float*)d_in[0];
  const int*   src = (const int*)d_in[1];
  const int*   dst = (const int*)d_in[2];
  const float* ew  = (const float*)d_in[3];
  const float* W[7]; const float* b[7];
  for (int i = 0; i < 7; ++i) {
    W[i] = (const float*)d_in[4 + 2 * i];
    b[i] = (const float*)d_in[5 + 2 * i];
  }
  int N = in_sizes[0] / NFEAT;   // 65536
  int E = in_sizes[1];           // 1048576

  char* ws = (char*)d_ws;
  int*      off     = (int*)(ws + 0);                 // (N+1) ints
  int*      bsum    = (int*)(ws + (1ll << 20));       // 256 ints
  int*      cnt     = (int*)(ws + (2ll << 20));       // N ints
  int2*     edata   = (int2*)(ws + (4ll << 20));      // E int2 = 8MB  [4,12)
  int*      rank    = (int*)(ws + (12ll << 20));      // E ints = 4MB  [12,16)
  ushort_t* support = (ushort_t*)(ws + (16ll << 20)); // N*64 bf16 = 8MB [16,24)
  float*    hA      = (float*)(ws + (32ll << 20));    // 16MB
  float*    hB      = (float*)(ws + (48ll << 20));    // 16MB

  // ---- build dst-CSR ----
  hipMemsetAsync(cnt, 0, (size_t)N * sizeof(int), stream);
  rank_k<<<(E + 255) / 256, 256, 0, stream>>>(dst, cnt, rank, E);
  int nb = (N + 255) / 256;  // 256 blocks
  scan1_k<<<nb, 256, 0, stream>>>(cnt, off, bsum, N);
  scan2_k<<<1, 256, 0, stream>>>(bsum, nb);
  scan3_k<<<nb, 256, 0, stream>>>(off, bsum, N, E);
  fill_k<<<(E + 255) / 256, 256, 0, stream>>>(src, dst, ew, off, rank, edata, E);

  int gb_gemm = N / 64;  // 1024 blocks
  int gb_agg  = N / 4;   // 4 waves per 256-thread block

  // L1: x[128] -> 64, relu
  gemm_k<128, 64><<<gb_gemm, 256, 0, stream>>>(x, W[0], support, N);
  agg_k<<<gb_agg, 256, 0, stream>>>(support, edata, off, b[0], nullptr, hA, N, 1);
  // L2
  gemm_k<64, 64><<<gb_gemm, 256, 0, stream>>>(hA, W[1], support, N);
  agg_k<<<gb_agg, 256, 0, stream>>>(support, edata, off, b[1], nullptr, hB, N, 1);
  // L3: + residual (h2 = hB)
  gemm_k<64, 64><<<gb_gemm, 256, 0, stream>>>(hB, W[2], support, N);
  agg_k<<<gb_agg, 256, 0, stream>>>(support, edata, off, b[2], hB, hA, N, 1);
  // L4: + residual (h3 = hA)
  gemm_k<64, 64><<<gb_gemm, 256, 0, stream>>>(hA, W[3], support, N);
  agg_k<<<gb_agg, 256, 0, stream>>>(support, edata, off, b[3], hA, hB, N, 1);
  // L5: + residual (h4 = hB)
  gemm_k<64, 64><<<gb_gemm, 256, 0, stream>>>(hB, W[4], support, N);
  agg_k<<<gb_agg, 256, 0, stream>>>(support, edata, off, b[4], hB, hA, N, 1);
  // L6
  gemm_k<64, 64><<<gb_gemm, 256, 0, stream>>>(hA, W[5], support, N);
  agg_k<<<gb_agg, 256, 0, stream>>>(support, edata, off, b[5], nullptr, hB, N, 1);
  // L7: 64 -> 40, + log_softmax
  gemm_k<64, 40><<<gb_gemm, 256, 0, stream>>>(hB, W[6], support, N);
  agg_final_k<<<gb_agg, 256, 0, stream>>>(support, edata, off, b[6], (float*)d_out, N);
}